// Round 9
// baseline (84.523 us; speedup 1.0000x reference)
//
#include <hip/hip_runtime.h>

#pragma clang fp contract(off)

namespace {
constexpr int B_ = 32;
constexpr int F_ = 512;
constexpr int BF_ = B_ * F_;             // 16384
constexpr long TBF_ = 16777216;          // T*B*F
constexpr int NITER = 10;
constexpr int NTHR = 512;                // 8 waves, 1 column each

typedef float v2f __attribute__((ext_vector_type(2)));

// exp(-4*(hc-0.7)) = 2^(-hc*K + 0.7K)
constexpr float KLOG = 5.770780163555852f;   // 4*log2(e)
constexpr float CLOG = 4.0395461144890964f;  // 0.7*4*log2(e)

// bijective swizzle of 16B-block index (bits 3..5 XORed into 0..2)
__device__ __forceinline__ int swz(int bb) { return bb ^ ((bb >> 3) & 7); }

template <int CTRL, int RM>
__device__ __forceinline__ float dppf(float oldv, float src) {
  return __builtin_bit_cast(
      float, __builtin_amdgcn_update_dpp(__builtin_bit_cast(int, oldv),
                                         __builtin_bit_cast(int, src), CTRL,
                                         RM, 0xf, false));
}

struct ABs { float A, B; };
// one scan step: P = shifted S (identity where masked), S = comb(P,S)
// comb(l,r): A = r.A*l.A ; B = r.A*l.B + r.B   (jax comb order)
template <int CTRL, int RM>
__device__ __forceinline__ ABs scan_step(ABs S) {
  ABs P;
  P.A = dppf<CTRL, RM>(1.0f, S.A);
  P.B = dppf<CTRL, RM>(0.0f, S.B);
  ABs o;
  o.A = S.A * P.A;
  o.B = __builtin_fmaf(S.A, P.B, S.B);
  return o;
}

__device__ __forceinline__ v2f pkfma(v2f a, v2f b, v2f c) {
  return __builtin_elementwise_fma(a, b, c);
}
}  // namespace

// bounds(512,4): cap 128 regs/wave (footprint ~95 -> no spill); runtime
// residency = floor(512/alloc) ~ 5 waves/SIMD.
__global__ __launch_bounds__(NTHR, 4) void deer_lif_kernel(
    const float* __restrict__ x, const float* __restrict__ v_init,
    float* __restrict__ out) {
  // 32 KB: 4 pair-regions x 2048 floats. 16B block bb=t>>1 of region pr
  // holds {x[2bb].c0, x[2bb].c1, x[2bb+1].c0, x[2bb+1].c1}, swizzled.
  __shared__ float smem[8192];

  // Bijective XCD swizzle: 2048 blocks = 8 XCDs x 256 contiguous ids.
  const int raw = blockIdx.x;
  const int blk = (raw & 7) * 256 + (raw >> 3);

  const int b  = blk >> 6;          // batch row (64 f-groups per row)
  const int f0 = (blk & 63) << 3;   // 8 consecutive f per block

  const int tid = threadIdx.x;
  const int rt = tid >> 1;          // 0..255
  const int c0 = (tid & 1) << 2;    // which float4 of the 8-col row
  const int wr0 = c0 >> 1;          // first pair-region this thread feeds

  // ---- stage x: coalesced 32B/row reads, transpose into swizzled LDS ----
  const float* xb = x + (long)b * F_ + f0 + c0;
#pragma unroll
  for (int p = 0; p < 4; ++p) {
    const int t = rt + (p << 8);
    const float4 v = *reinterpret_cast<const float4*>(xb + (long)t * BF_);
    const int base = (swz(t >> 1) << 2) + ((t & 1) << 1);
    *reinterpret_cast<float2*>(&smem[wr0 * 2048 + base]) =
        make_float2(v.x, v.y);
    *reinterpret_cast<float2*>(&smem[(wr0 + 1) * 2048 + base]) =
        make_float2(v.z, v.w);
  }
  __syncthreads();

  const int w = tid >> 6;           // wave id; owns column f0+w
  const int lane = tid & 63;
  const bool lz = (lane == 0);
  // this wave's column: pair-region w>>1, half w&1. cb[4*swz(bb)] = x[2bb],
  // cb[4*swz(bb)+2] = x[2bb+1].
  float* cb = &smem[(w >> 1) * 2048 + (w & 1)];

  // per-lane relative float offsets of its 8 16B blocks (pre-swizzled)
  int fo[8];
#pragma unroll
  for (int p = 0; p < 8; ++p) fo[p] = swz((lane << 3) + p) << 2;

  const float v0 = v_init[b * F_ + f0 + w];

  // ---- warmstart: 2 steps of continuous dynamics on lane 0, rest zeros ----
  v2f y2[8];  // y2[p] = {y[2p], y[2p+1]} of prev iterate
#pragma unroll
  for (int p = 0; p < 8; ++p) y2[p] = (v2f){0.0f, 0.0f};
  if (lz) {
    const float x0 = cb[0], x1 = cb[2];   // swz(0)=0
    const float h0 = v0 + (x0 - v0) * 0.5f;
    const float h1 = h0 + (x1 - h0) * 0.5f;
    y2[0] = (v2f){h0, h1};
  }

  const v2f half2 = {0.5f, 0.5f};
  const v2f one2 = {1.0f, 1.0f};
  const v2f nk2 = {-KLOG, -KLOG};
  const v2f ck2 = {CLOG, CLOG};
  const v2f lo2 = {-20.0f, -20.0f};
  const v2f m22 = {-2.0f, -2.0f};

#pragma unroll 1
  for (int it = 0; it < NITER; ++it) {
    // ys for this lane's first element = prev lane's y[15]; lane0 -> v0
    const float ys0 = dppf<0x138, 0xf>(v0, y2[7].y);  // WAVE_SHR1

    // ---- elementwise coeffs, v2f-packed over adjacent t (both ys from
    // prev iterate -> independent) ----
    v2f a2[8], r2[8];
#pragma unroll
    for (int p = 0; p < 8; ++p) {
      v2f xj;
      xj.x = cb[fo[p]];
      xj.y = cb[fo[p] + 2];
      v2f ys;
      ys.x = (p == 0) ? ys0 : y2[p - 1].y;
      ys.y = y2[p].x;
      const v2f d = xj - ys;
      const v2f h = pkfma(d, half2, ys);            // exact *0.5
      // lower clamp only: h>20 saturates to a=0.5 exactly (matches clip)
      const v2f hc = __builtin_elementwise_max(h, lo2);
      const v2f z = pkfma(hc, nk2, ck2);
      v2f e;
      e.x = __builtin_amdgcn_exp2f(z.x);
      e.y = __builtin_amdgcn_exp2f(z.y);
      const v2f den = one2 + e;
      v2f s;
      s.x = __builtin_amdgcn_rcpf(den.x);
      s.y = __builtin_amdgcn_rcpf(den.y);
      const v2f oms = one2 - s;
      const v2f pp = s * oms;                        // s(1-s)
      const v2f aj = pkfma(pp, m22, half2);          // a = 0.5 - 2s(1-s)
      const v2f rj = pkfma(-aj, ys, h);              // rhs = h - a*ys
      a2[p] = aj;
      r2[p] = rj;
    }

    // ---- compose: pairs (elems 2p,2p+1) ----
    float pA[8], pB[8];
#pragma unroll
    for (int p = 0; p < 8; ++p) {
      pA[p] = a2[p].y * a2[p].x;
      pB[p] = __builtin_fmaf(a2[p].y, r2[p].x, r2[p].y);
    }
    // quarters (pairs 2i,2i+1) -- 4 independent + serial tree
    float qA[4], qB[4];
#pragma unroll
    for (int i = 0; i < 4; ++i) {
      qA[i] = pA[2 * i + 1] * pA[2 * i];
      qB[i] = __builtin_fmaf(pA[2 * i + 1], pB[2 * i], pB[2 * i + 1]);
    }
    const float c01A = qA[1] * qA[0];
    const float c01B = __builtin_fmaf(qA[1], qB[0], qB[1]);
    const float c012A = qA[2] * c01A;
    const float c012B = __builtin_fmaf(qA[2], c01B, qB[2]);
    ABs S;
    S.A = qA[3] * c012A;
    S.B = __builtin_fmaf(qA[3], c012B, qB[3]);

    // ---- 64-lane inclusive affine scan, all-DPP, scalar ----
    S = scan_step<0x111, 0xf>(S);  // row_shr:1
    S = scan_step<0x112, 0xf>(S);  // row_shr:2
    S = scan_step<0x114, 0xf>(S);  // row_shr:4
    S = scan_step<0x118, 0xf>(S);  // row_shr:8
    S = scan_step<0x142, 0xa>(S);  // row_bcast:15 -> rows 1,3
    S = scan_step<0x143, 0xc>(S);  // row_bcast:31 -> rows 2,3

    // carry into this lane = value at end of previous lane (lane0 -> v0)
    const float cinc = __builtin_fmaf(S.A, v0, S.B);
    const float cin = dppf<0x138, 0xf>(v0, cinc);  // WAVE_SHR1

    // ---- apply: quarter seeds, then 2 packed fmas per quarter
    // (y[4i]   = a[4i]*si + r[4i],  y[4i+1] = pA*si + pB;
    //  y[4i+2] = a*y[4i+1] + r,     y[4i+3] = pA*y[4i+1] + pB) ----
    const float s1 = __builtin_fmaf(qA[0], cin, qB[0]);
    const float s2 = __builtin_fmaf(c01A, cin, c01B);
    const float s3 = __builtin_fmaf(c012A, cin, c012B);
#pragma unroll
    for (int i = 0; i < 4; ++i) {
      const float si = (i == 0) ? cin : (i == 1) ? s1 : (i == 2) ? s2 : s3;
      v2f m1, b1;
      m1.x = a2[2 * i].x;  m1.y = pA[2 * i];
      b1.x = r2[2 * i].x;  b1.y = pB[2 * i];
      const v2f w1 = pkfma(m1, (v2f){si, si}, b1);
      y2[2 * i] = w1;
      v2f m2, b2;
      m2.x = a2[2 * i + 1].x;  m2.y = pA[2 * i + 1];
      b2.x = r2[2 * i + 1].x;  b2.y = pB[2 * i + 1];
      const v2f w2 = pkfma(m2, (v2f){w1.y, w1.y}, b2);
      y2[2 * i + 1] = w2;
    }
  }

  // ---- stage y back over x (this wave's half of its pair-region only;
  // the other wave's x lives at disjoint offsets -> no race, no barrier) ----
#pragma unroll
  for (int p = 0; p < 8; ++p) {
    cb[fo[p]] = y2[p].x;
    cb[fo[p] + 2] = y2[p].y;
  }
  __syncthreads();

  // ---- emit spike + y with 32B/row coalesced stores ----
  float* outs = out;          // spike
  float* outy = out + TBF_;   // y
  const long cbg = (long)b * F_ + f0 + c0;
#pragma unroll
  for (int p = 0; p < 4; ++p) {
    const int t = rt + (p << 8);
    const int base = (swz(t >> 1) << 2) + ((t & 1) << 1);
    const float2 lo = *reinterpret_cast<const float2*>(&smem[wr0 * 2048 + base]);
    const float2 h2 =
        *reinterpret_cast<const float2*>(&smem[(wr0 + 1) * 2048 + base]);
    const float4 yv = make_float4(lo.x, lo.y, h2.x, h2.y);
    const float4 sv = make_float4(yv.x >= 0.7f ? 1.0f : 0.0f,
                                  yv.y >= 0.7f ? 1.0f : 0.0f,
                                  yv.z >= 0.7f ? 1.0f : 0.0f,
                                  yv.w >= 0.7f ? 1.0f : 0.0f);
    const long off = (long)t * BF_ + cbg;
    *reinterpret_cast<float4*>(outy + off) = yv;
    *reinterpret_cast<float4*>(outs + off) = sv;
  }
}

extern "C" void kernel_launch(void* const* d_in, const int* in_sizes, int n_in,
                              void* d_out, int out_size, void* d_ws, size_t ws_size,
                              hipStream_t stream) {
  const float* x = (const float*)d_in[0];
  const float* v_init = (const float*)d_in[1];
  float* out = (float*)d_out;
  deer_lif_kernel<<<dim3(2048), dim3(NTHR), 0, stream>>>(x, v_init, out);
}

// Round 10
// 84.083 us; speedup vs baseline: 1.0052x; 1.0052x over previous
//
#include <hip/hip_runtime.h>

#pragma clang fp contract(off)

namespace {
constexpr int B_ = 32;
constexpr int F_ = 512;
constexpr int BF_ = B_ * F_;             // 16384
constexpr long TBF_ = 16777216;          // T*B*F
constexpr int NITER = 10;
constexpr int NTHR = 512;                // 8 waves, 1 column each

typedef float v2f __attribute__((ext_vector_type(2)));

// exp(-4*(hc-0.7)) = 2^(-hc*K + 0.7K)
constexpr float KLOG = 5.770780163555852f;   // 4*log2(e)
constexpr float CLOG = 4.0395461144890964f;  // 0.7*4*log2(e)

// bijective swizzle of float4-block index (bits 3..5 XORed into 0..2):
// per-lane stride-64B ds_read_b128 conflict-free (R3-measured: 1.31M total).
__device__ __forceinline__ int swz(int bb) { return bb ^ ((bb >> 3) & 7); }

template <int CTRL, int RM>
__device__ __forceinline__ float dppf(float oldv, float src) {
  return __builtin_bit_cast(
      float, __builtin_amdgcn_update_dpp(__builtin_bit_cast(int, oldv),
                                         __builtin_bit_cast(int, src), CTRL,
                                         RM, 0xf, false));
}

struct ABs { float A, B; };
// one scan step: P = shifted S (identity where masked), S = comb(P,S)
// comb(l,r): A = r.A*l.A ; B = r.A*l.B + r.B   (jax comb order)
template <int CTRL, int RM>
__device__ __forceinline__ ABs scan_step(ABs S) {
  ABs P;
  P.A = dppf<CTRL, RM>(1.0f, S.A);
  P.B = dppf<CTRL, RM>(0.0f, S.B);
  ABs o;
  o.A = S.A * P.A;
  o.B = __builtin_fmaf(S.A, P.B, S.B);
  return o;
}

__device__ __forceinline__ v2f pkfma(v2f a, v2f b, v2f c) {
  return __builtin_elementwise_fma(a, b, c);
}
}  // namespace

// bounds(512,4): cap 128 unified regs/wave; footprint ~105 -> no spill,
// 4 waves/SIMD resident.
__global__ __launch_bounds__(NTHR, 4) void deer_lif_kernel(
    const float* __restrict__ x, const float* __restrict__ v_init,
    float* __restrict__ out) {
  // 32 KB: 8 column-regions x 1024 floats. x[t] of column w at float
  // offset (w<<10) + (swz(t>>2)<<2) + (t&3). Used ONLY for the in/out
  // transposes; x lives in registers during all 10 sweeps.
  __shared__ float smem[8192];

  // Bijective XCD swizzle: 2048 blocks = 8 XCDs x 256 contiguous ids.
  const int raw = blockIdx.x;
  const int blk = (raw & 7) * 256 + (raw >> 3);

  const int b  = blk >> 6;          // batch row (64 f-groups per row)
  const int f0 = (blk & 63) << 3;   // 8 consecutive f per block

  const int tid = threadIdx.x;
  const int rt = tid >> 1;          // 0..255
  const int c0 = (tid & 1) << 2;    // which float4 of the 8-col row

  // ---- stage x: coalesced 32B/row reads, transpose into swizzled LDS ----
  const float* xb = x + (long)b * F_ + f0 + c0;
#pragma unroll
  for (int p = 0; p < 4; ++p) {
    const int t = rt + (p << 8);
    const float4 v = *reinterpret_cast<const float4*>(xb + (long)t * BF_);
    const int base = (swz(t >> 2) << 2) + (t & 3);
    smem[(c0 + 0) * 1024 + base] = v.x;
    smem[(c0 + 1) * 1024 + base] = v.y;
    smem[(c0 + 2) * 1024 + base] = v.z;
    smem[(c0 + 3) * 1024 + base] = v.w;
  }
  __syncthreads();

  const int w = tid >> 6;           // wave id; owns column f0+w
  const int lane = tid & 63;
  const bool lz = (lane == 0);

  // ---- x -> registers, packed over adjacent t: xp2[p] = {x[2p], x[2p+1]} ----
  v2f xp2[8];
#pragma unroll
  for (int q = 0; q < 4; ++q) {
    const int off = (w << 10) + (swz((lane << 2) + q) << 2);
    const float4 v = *reinterpret_cast<const float4*>(&smem[off]);
    xp2[2 * q] = (v2f){v.x, v.y};
    xp2[2 * q + 1] = (v2f){v.z, v.w};
  }

  const float v0 = v_init[b * F_ + f0 + w];

  // ---- warmstart: 2 steps of continuous dynamics on lane 0, rest zeros ----
  v2f y2[8];  // y2[p] = {y[2p], y[2p+1]} of prev iterate
#pragma unroll
  for (int p = 0; p < 8; ++p) y2[p] = (v2f){0.0f, 0.0f};
  if (lz) {
    const float h0 = v0 + (xp2[0].x - v0) * 0.5f;
    const float h1 = h0 + (xp2[0].y - h0) * 0.5f;
    y2[0] = (v2f){h0, h1};
  }

  const v2f half2 = {0.5f, 0.5f};
  const v2f one2 = {1.0f, 1.0f};
  const v2f nk2 = {-KLOG, -KLOG};
  const v2f ck2 = {CLOG, CLOG};
  const v2f lo2 = {-20.0f, -20.0f};
  const v2f m22 = {-2.0f, -2.0f};

#pragma unroll 1
  for (int it = 0; it < NITER; ++it) {
    // ys for this lane's first element = prev lane's y[15]; lane0 -> v0
    const float ys0 = dppf<0x138, 0xf>(v0, y2[7].y);  // WAVE_SHR1

    // ---- elementwise coeffs, v2f-packed over adjacent t (both ys from
    // prev iterate -> independent) ----
    v2f a2[8], r2[8];
#pragma unroll
    for (int p = 0; p < 8; ++p) {
      const v2f xj = xp2[p];
      v2f ys;
      ys.x = (p == 0) ? ys0 : y2[p - 1].y;
      ys.y = y2[p].x;
      const v2f d = xj - ys;
      const v2f h = pkfma(d, half2, ys);            // exact *0.5
      // lower clamp only: h>20 saturates to a=0.5 exactly (matches clip)
      const v2f hc = __builtin_elementwise_max(h, lo2);
      const v2f z = pkfma(hc, nk2, ck2);
      v2f e;
      e.x = __builtin_amdgcn_exp2f(z.x);
      e.y = __builtin_amdgcn_exp2f(z.y);
      const v2f den = one2 + e;
      v2f s;
      s.x = __builtin_amdgcn_rcpf(den.x);
      s.y = __builtin_amdgcn_rcpf(den.y);
      const v2f oms = one2 - s;
      const v2f pp = s * oms;                        // s(1-s)
      const v2f aj = pkfma(pp, m22, half2);          // a = 0.5 - 2s(1-s)
      const v2f rj = pkfma(-aj, ys, h);              // rhs = h - a*ys
      a2[p] = aj;
      r2[p] = rj;
    }

    // ---- compose: pairs (elems 2p,2p+1) ----
    float pA[8], pB[8];
#pragma unroll
    for (int p = 0; p < 8; ++p) {
      pA[p] = a2[p].y * a2[p].x;
      pB[p] = __builtin_fmaf(a2[p].y, r2[p].x, r2[p].y);
    }
    // quarters (pairs 2i,2i+1) -- 4 independent + serial tree
    float qA[4], qB[4];
#pragma unroll
    for (int i = 0; i < 4; ++i) {
      qA[i] = pA[2 * i + 1] * pA[2 * i];
      qB[i] = __builtin_fmaf(pA[2 * i + 1], pB[2 * i], pB[2 * i + 1]);
    }
    const float c01A = qA[1] * qA[0];
    const float c01B = __builtin_fmaf(qA[1], qB[0], qB[1]);
    const float c012A = qA[2] * c01A;
    const float c012B = __builtin_fmaf(qA[2], c01B, qB[2]);
    ABs S;
    S.A = qA[3] * c012A;
    S.B = __builtin_fmaf(qA[3], c012B, qB[3]);

    // ---- 64-lane inclusive affine scan, all-DPP, scalar ----
    S = scan_step<0x111, 0xf>(S);  // row_shr:1
    S = scan_step<0x112, 0xf>(S);  // row_shr:2
    S = scan_step<0x114, 0xf>(S);  // row_shr:4
    S = scan_step<0x118, 0xf>(S);  // row_shr:8
    S = scan_step<0x142, 0xa>(S);  // row_bcast:15 -> rows 1,3
    S = scan_step<0x143, 0xc>(S);  // row_bcast:31 -> rows 2,3

    // carry into this lane = value at end of previous lane (lane0 -> v0)
    const float cinc = __builtin_fmaf(S.A, v0, S.B);
    const float cin = dppf<0x138, 0xf>(v0, cinc);  // WAVE_SHR1

    // ---- apply: quarter seeds, then 2 packed fmas per quarter ----
    const float s1 = __builtin_fmaf(qA[0], cin, qB[0]);
    const float s2 = __builtin_fmaf(c01A, cin, c01B);
    const float s3 = __builtin_fmaf(c012A, cin, c012B);
#pragma unroll
    for (int i = 0; i < 4; ++i) {
      const float si = (i == 0) ? cin : (i == 1) ? s1 : (i == 2) ? s2 : s3;
      v2f m1, b1;
      m1.x = a2[2 * i].x;  m1.y = pA[2 * i];
      b1.x = r2[2 * i].x;  b1.y = pB[2 * i];
      const v2f w1 = pkfma(m1, (v2f){si, si}, b1);
      y2[2 * i] = w1;
      v2f m2, b2;
      m2.x = a2[2 * i + 1].x;  m2.y = pA[2 * i + 1];
      b2.x = r2[2 * i + 1].x;  b2.y = pB[2 * i + 1];
      const v2f w2 = pkfma(m2, (v2f){w1.y, w1.y}, b2);
      y2[2 * i + 1] = w2;
    }
  }

  // ---- stage y back over x (own region only; conflict-free b128) ----
#pragma unroll
  for (int q = 0; q < 4; ++q) {
    const int off = (w << 10) + (swz((lane << 2) + q) << 2);
    float4 v;
    v.x = y2[2 * q].x;
    v.y = y2[2 * q].y;
    v.z = y2[2 * q + 1].x;
    v.w = y2[2 * q + 1].y;
    *reinterpret_cast<float4*>(&smem[off]) = v;
  }
  __syncthreads();

  // ---- emit spike + y with 32B/row coalesced stores ----
  float* outs = out;          // spike
  float* outy = out + TBF_;   // y
  const long cbg = (long)b * F_ + f0 + c0;
#pragma unroll
  for (int p = 0; p < 4; ++p) {
    const int t = rt + (p << 8);
    const int base = (swz(t >> 2) << 2) + (t & 3);
    float4 yv;
    yv.x = smem[(c0 + 0) * 1024 + base];
    yv.y = smem[(c0 + 1) * 1024 + base];
    yv.z = smem[(c0 + 2) * 1024 + base];
    yv.w = smem[(c0 + 3) * 1024 + base];
    const float4 sv = make_float4(yv.x >= 0.7f ? 1.0f : 0.0f,
                                  yv.y >= 0.7f ? 1.0f : 0.0f,
                                  yv.z >= 0.7f ? 1.0f : 0.0f,
                                  yv.w >= 0.7f ? 1.0f : 0.0f);
    const long off = (long)t * BF_ + cbg;
    *reinterpret_cast<float4*>(outy + off) = yv;
    *reinterpret_cast<float4*>(outs + off) = sv;
  }
}

extern "C" void kernel_launch(void* const* d_in, const int* in_sizes, int n_in,
                              void* d_out, int out_size, void* d_ws, size_t ws_size,
                              hipStream_t stream) {
  const float* x = (const float*)d_in[0];
  const float* v_init = (const float*)d_in[1];
  float* out = (float*)d_out;
  deer_lif_kernel<<<dim3(2048), dim3(NTHR), 0, stream>>>(x, v_init, out);
}

// Round 12
// 69.317 us; speedup vs baseline: 1.2194x; 1.2130x over previous
//
#include <hip/hip_runtime.h>

#pragma clang fp contract(off)

namespace {
constexpr int B_ = 32;
constexpr int F_ = 512;
constexpr int BF_ = B_ * F_;             // 16384
constexpr long TBF_ = 16777216;          // T*B*F
constexpr int NITER = 10;
constexpr int NTHR = 256;                // 4 waves, 2 columns each

typedef float v2f __attribute__((ext_vector_type(2)));

// exp(-4*(hc-0.7)) = 2^(-hc*K + 0.7K)
constexpr float KLOG = 5.770780163555852f;   // 4*log2(e)
constexpr float CLOG = 4.0395461144890964f;  // 0.7*4*log2(e)

// bijective swizzle of 16B-block index (bits 3..5 XORed into 0..2):
// makes the stride-128B per-lane ds_read_b128 pattern conflict-free.
__device__ __forceinline__ int swz(int bb) { return bb ^ ((bb >> 3) & 7); }

struct ABp { v2f A, B; };
// combine(left, right) of affine maps v -> A*v + B (jax comb order), packed
__device__ __forceinline__ ABp combp(ABp l, ABp r) {
  ABp o;
  o.A = r.A * l.A;
  o.B = __builtin_elementwise_fma(r.A, l.B, r.B);
  return o;
}

template <int CTRL, int RM>
__device__ __forceinline__ float dppf(float oldv, float src) {
  return __builtin_bit_cast(
      float, __builtin_amdgcn_update_dpp(__builtin_bit_cast(int, oldv),
                                         __builtin_bit_cast(int, src), CTRL,
                                         RM, 0xf, false));
}

// one scan step: P = shifted S (identity where invalid/masked), S = comb(P,S)
template <int CTRL, int RM>
__device__ __forceinline__ ABp scan_step(ABp S) {
  ABp P;
  P.A.x = dppf<CTRL, RM>(1.0f, S.A.x);
  P.A.y = dppf<CTRL, RM>(1.0f, S.A.y);
  P.B.x = dppf<CTRL, RM>(0.0f, S.B.x);
  P.B.y = dppf<CTRL, RM>(0.0f, S.B.y);
  return combp(P, S);
}

__device__ __forceinline__ v2f pkfma(v2f a, v2f b, v2f c) {
  return __builtin_elementwise_fma(a, b, c);
}
}  // namespace

__global__ __launch_bounds__(NTHR, 3) void deer_lif_kernel(
    const float* __restrict__ x, const float* __restrict__ v_init,
    float* __restrict__ out) {
  // 32 KB, flat floats: per wave an 8 KB region of 512 16B blocks; block
  // bb = t>>1 holds (x[t],x[t+1]) x (col even, col odd), swizzled by swz().
  __shared__ float smem[8192];

  // Bijective XCD swizzle: 2048 blocks = 8 XCDs x 256 contiguous ids.
  const int raw = blockIdx.x;
  const int blk = (raw & 7) * 256 + (raw >> 3);

  const int b  = blk >> 6;          // batch row (64 f-groups per row)
  const int f0 = (blk & 63) << 3;   // 8 consecutive f per block

  const int tid = threadIdx.x;
  const int rt = tid >> 1;          // row within 128-row pass
  const int c0 = (tid & 1) << 2;    // which float4 of the 8-col row
  const int wr0 = c0 >> 1;          // first wave-region this thread feeds

  // ---- stage x: coalesced 32B/row reads, transpose into swizzled LDS ----
  const float* xb = x + (long)b * F_ + f0 + c0;
#pragma unroll
  for (int p = 0; p < 8; ++p) {
    const int t = rt + (p << 7);
    const float4 v = *reinterpret_cast<const float4*>(xb + (long)t * BF_);
    const int base = (swz(t >> 1) << 2) + ((t & 1) << 1);
    *reinterpret_cast<float2*>(&smem[wr0 * 2048 + base]) =
        make_float2(v.x, v.y);
    *reinterpret_cast<float2*>(&smem[(wr0 + 1) * 2048 + base]) =
        make_float2(v.z, v.w);
  }
  __syncthreads();

  const int w = tid >> 6;           // wave id; owns columns 2w, 2w+1
  const int lane = tid & 63;
  const bool lz = (lane == 0);

  const float2 vi =
      *reinterpret_cast<const float2*>(&v_init[b * F_ + f0 + 2 * w]);
  v2f v0 = {vi.x, vi.y};

  // ---- x lives in registers for all 10 sweeps (packed over 2 columns) ----
  v2f xp[16];
#pragma unroll
  for (int q = 0; q < 8; ++q) {
    const int bbs = swz((lane << 3) + q);
    const float4 v =
        *reinterpret_cast<const float4*>(&smem[w * 2048 + (bbs << 2)]);
    xp[2 * q].x = v.x;
    xp[2 * q].y = v.y;
    xp[2 * q + 1].x = v.z;
    xp[2 * q + 1].y = v.w;
  }

  // ---- warmstart: 2 steps of continuous dynamics on lane 0, rest zeros ----
  v2f y[16];
#pragma unroll
  for (int j = 0; j < 16; ++j) y[j] = (v2f){0.0f, 0.0f};
  if (lz) {
    const v2f h0 = v0 + (xp[0] - v0) * 0.5f;
    const v2f h1 = h0 + (xp[1] - h0) * 0.5f;
    y[0] = h0;
    y[1] = h1;
  }

  const v2f half2 = {0.5f, 0.5f};
  const v2f one2 = {1.0f, 1.0f};
  const v2f nk2 = {-KLOG, -KLOG};
  const v2f ck2 = {CLOG, CLOG};
  const v2f lo2 = {-20.0f, -20.0f};
  const v2f m22 = {-2.0f, -2.0f};

#pragma unroll 1
  for (int it = 0; it < NITER; ++it) {
    // ys for this lane's first element = prev lane's y[15]; lane0 -> v0
    v2f ys0;
    ys0.x = dppf<0x138, 0xf>(v0.x, y[15].x);  // WAVE_SHR1
    ys0.y = dppf<0x138, 0xf>(v0.y, y[15].y);

    // ---- packed elementwise coeffs (independent per j) ----
    v2f a[16], r[16];
#pragma unroll
    for (int j = 0; j < 16; ++j) {
      const v2f ys = (j == 0) ? ys0 : y[j - 1];
      const v2f d = xp[j] - ys;
      const v2f h = pkfma(d, half2, ys);            // exact *0.5
      // lower clamp: bounds den <= 2^119.5 (paired-rcp overflow safety);
      // h>20 saturates to a=0.5 exactly without the upper clamp.
      const v2f hc = __builtin_elementwise_max(h, lo2);
      const v2f z = pkfma(hc, nk2, ck2);
      v2f e;
      e.x = __builtin_amdgcn_exp2f(z.x);
      e.y = __builtin_amdgcn_exp2f(z.y);
      const v2f den = e + one2;
      // paired reciprocal: one rcp serves both elements.
      const float dd = den.x * den.y;
      const float rc = __builtin_amdgcn_rcpf(dd);
      v2f s;
      s.x = den.y * rc;                              // 1/den.x
      s.y = den.x * rc;                              // 1/den.y
      const v2f pp = __builtin_elementwise_fma(s, -s, s);  // s(1-s), 1 op
      const v2f aj = pkfma(pp, m22, half2);          // a = 0.5 - 2s(1-s)
      const v2f rj = pkfma(-aj, ys, h);              // rhs = h - a*ys
      a[j] = aj;
      r[j] = rj;
    }

    // ---- compose: 4 independent 4-deep quarter chains (ILP x4) ----
    v2f qA0 = a[0], qB0 = r[0];
    v2f qA1 = a[4], qB1 = r[4];
    v2f qA2 = a[8], qB2 = r[8];
    v2f qA3 = a[12], qB3 = r[12];
#pragma unroll
    for (int k = 1; k < 4; ++k) {
      qA0 = qA0 * a[k];      qB0 = pkfma(qB0, a[k], r[k]);
      qA1 = qA1 * a[4 + k];  qB1 = pkfma(qB1, a[4 + k], r[4 + k]);
      qA2 = qA2 * a[8 + k];  qB2 = pkfma(qB2, a[8 + k], r[8 + k]);
      qA3 = qA3 * a[12 + k]; qB3 = pkfma(qB3, a[12 + k], r[12 + k]);
    }
    // serial tree yields quarter prefixes for the apply entries
    const v2f c01A = qA0 * qA1, c01B = pkfma(qB0, qA1, qB1);
    const v2f c012A = c01A * qA2, c012B = pkfma(c01B, qA2, qB2);
    ABp S;
    S.A = c012A * qA3;
    S.B = pkfma(c012B, qA3, qB3);

    // ---- 64-lane inclusive affine scan, all-DPP, packed over 2 cols ----
    S = scan_step<0x111, 0xf>(S);  // row_shr:1
    S = scan_step<0x112, 0xf>(S);  // row_shr:2
    S = scan_step<0x114, 0xf>(S);  // row_shr:4
    S = scan_step<0x118, 0xf>(S);  // row_shr:8
    S = scan_step<0x142, 0xa>(S);  // row_bcast:15 -> rows 1,3
    S = scan_step<0x143, 0xc>(S);  // row_bcast:31 -> rows 2,3

    // carry into this lane = value at end of previous lane (lane0 -> v0)
    const v2f cinc = pkfma(S.A, v0, S.B);
    v2f cin;
    cin.x = dppf<0x138, 0xf>(v0.x, cinc.x);  // WAVE_SHR1
    cin.y = dppf<0x138, 0xf>(v0.y, cinc.y);

    // ---- apply: 4 independent 4-deep chains seeded by quarter prefixes ----
    v2f t0 = cin;
    v2f t1 = pkfma(qA0, cin, qB0);
    v2f t2 = pkfma(c01A, cin, c01B);
    v2f t3 = pkfma(c012A, cin, c012B);
#pragma unroll
    for (int k = 0; k < 4; ++k) {
      t0 = pkfma(a[k], t0, r[k]);           y[k] = t0;
      t1 = pkfma(a[4 + k], t1, r[4 + k]);   y[4 + k] = t1;
      t2 = pkfma(a[8 + k], t2, r[8 + k]);   y[8 + k] = t2;
      t3 = pkfma(a[12 + k], t3, r[12 + k]); y[12 + k] = t3;
    }
  }

  // ---- stage y back (same swizzle; wave only touches its own region) ----
#pragma unroll
  for (int q = 0; q < 8; ++q) {
    const int bbs = swz((lane << 3) + q);
    float4 v;
    v.x = y[2 * q].x;
    v.y = y[2 * q].y;
    v.z = y[2 * q + 1].x;
    v.w = y[2 * q + 1].y;
    *reinterpret_cast<float4*>(&smem[w * 2048 + (bbs << 2)]) = v;
  }
  __syncthreads();

  // ---- emit spike + y with 32B/row coalesced stores ----
  float* outs = out;          // spike
  float* outy = out + TBF_;   // y
  const long cb = (long)b * F_ + f0 + c0;
#pragma unroll
  for (int p = 0; p < 8; ++p) {
    const int t = rt + (p << 7);
    const int base = (swz(t >> 1) << 2) + ((t & 1) << 1);
    const float2 lo = *reinterpret_cast<const float2*>(&smem[wr0 * 2048 + base]);
    const float2 h2 =
        *reinterpret_cast<const float2*>(&smem[(wr0 + 1) * 2048 + base]);
    const float4 yv = make_float4(lo.x, lo.y, h2.x, h2.y);
    const float4 sv = make_float4(yv.x >= 0.7f ? 1.0f : 0.0f,
                                  yv.y >= 0.7f ? 1.0f : 0.0f,
                                  yv.z >= 0.7f ? 1.0f : 0.0f,
                                  yv.w >= 0.7f ? 1.0f : 0.0f);
    const long off = (long)t * BF_ + cb;
    *reinterpret_cast<float4*>(outy + off) = yv;
    *reinterpret_cast<float4*>(outs + off) = sv;
  }
}

extern "C" void kernel_launch(void* const* d_in, const int* in_sizes, int n_in,
                              void* d_out, int out_size, void* d_ws, size_t ws_size,
                              hipStream_t stream) {
  const float* x = (const float*)d_in[0];
  const float* v_init = (const float*)d_in[1];
  float* out = (float*)d_out;
  deer_lif_kernel<<<dim3(2048), dim3(NTHR), 0, stream>>>(x, v_init, out);
}